// Round 16
// baseline (87.523 us; speedup 1.0000x reference)
//
#include <hip/hip_runtime.h>
#include <hip/hip_bf16.h>

// Dynamic conv2d: B=16, C_in=64, H=W=128, C_out=64, K=5, ks=3, pad=1.
// R16 = R6's register/phase structure (A[36] in regs, acc16+pv16 reused,
// 4-slot bf16 ring, reg-staged write16 covered by MFMA) in a 4-wave
// (256-thr) full-width block -> 2 blocks/CU (133KB LDS, (256,2)).
// Cross-block TLP: each SIMD hosts one wave of each block; baranrier stalls
// of one block overlap the other block's compute. 4-row strips, 512 blocks.

typedef __attribute__((ext_vector_type(8))) __bf16 bf16x8;
typedef __attribute__((ext_vector_type(16))) float f32x16;
typedef __attribute__((ext_vector_type(4))) unsigned int u32x4;

#define NB 16
#define CI 64
#define CO 64
#define HH 128
#define WW 128
#define KBANK 5
#define ASTR 36864            // shorts of aggw per b: 2m * 36ks * 2g * 32co5 * 8j

__device__ __forceinline__ unsigned short f2bfu(float f) {
    __hip_bfloat16 h = __float2bfloat16(f);
    unsigned short s;
    __builtin_memcpy(&s, &h, 2);
    return s;
}

// ---------------- kernel 1: aggregate weights + bias ----------------
// aggw per b: [m(2)][ks(36)][g(2)][co5(32)][j(8)]; k = ks*16+g*8+j,
// tap = k>>6, ci = k&63, co = m*32+co5. Wave A-load = contiguous 1KB.
__global__ void prep_kernel(const float* __restrict__ weights,
                            const float* __restrict__ Wbank,
                            const float* __restrict__ bbank,
                            short* __restrict__ aggw,
                            float* __restrict__ aggb) {
    int idx = blockIdx.x * 256 + threadIdx.x;          // < 16*36864
    int b   = idx / ASTR;
    int rem = idx - b * ASTR;
    int j   = rem & 7;
    int co5 = (rem >> 3) & 31;
    int g   = (rem >> 8) & 1;
    int mk  = rem >> 9;
    int m   = mk / 36;
    int ks  = mk - m * 36;
    int co  = m * 32 + co5;
    int k   = ks * 16 + g * 8 + j;
    int tap = k >> 6;
    int ci  = k & 63;
    float s = 0.f;
#pragma unroll
    for (int kk = 0; kk < KBANK; ++kk)
        s += weights[b * KBANK + kk] * Wbank[((kk * CO + co) * CI + ci) * 9 + tap];
    aggw[idx] = (short)f2bfu(s);
    if (k == 0) {
        float sb = 0.f;
#pragma unroll
        for (int kk = 0; kk < KBANK; ++kk)
            sb += weights[b * KBANK + kk] * bbank[kk * CO + co];
        aggb[b * CO + co] = sb;
    }
}

// ---------------- kernel 2: streaming conv, 4-wave full-width blocks ----------------
__device__ __forceinline__ void load16(const float* __restrict__ xb, int r,
                                       int w, int scg, float (&pv)[16]) {
#pragma unroll
    for (int i = 0; i < 16; ++i)
        pv[i] = xb[((size_t)(scg * 16 + i) * HH + r) * WW + w];
}

__device__ __forceinline__ void zero16(float (&pv)[16]) {
#pragma unroll
    for (int i = 0; i < 16; ++i) pv[i] = 0.f;
}

// ring slot: [ch 8][pix 130][8 shorts]; pix = input w + 1.
__device__ __forceinline__ void write16(short* __restrict__ slot, int w, int scg,
                                        const float (&pv)[16]) {
#pragma unroll
    for (int h = 0; h < 2; ++h) {
        unsigned u0 = (unsigned)f2bfu(pv[h * 8 + 0]) | ((unsigned)f2bfu(pv[h * 8 + 1]) << 16);
        unsigned u1 = (unsigned)f2bfu(pv[h * 8 + 2]) | ((unsigned)f2bfu(pv[h * 8 + 3]) << 16);
        unsigned u2 = (unsigned)f2bfu(pv[h * 8 + 4]) | ((unsigned)f2bfu(pv[h * 8 + 5]) << 16);
        unsigned u3 = (unsigned)f2bfu(pv[h * 8 + 6]) | ((unsigned)f2bfu(pv[h * 8 + 7]) << 16);
        *(u32x4*)&slot[((scg * 2 + h) * 130 + w + 1) * 8] = u32x4{u0, u1, u2, u3};
    }
}

#define WAITL0   asm volatile("s_waitcnt lgkmcnt(0)" ::: "memory")
#define SBAR     do { __builtin_amdgcn_s_barrier(); __builtin_amdgcn_sched_barrier(0); } while (0)

__global__ __launch_bounds__(256, 2) void conv_kernel(const float* __restrict__ x,
                                                      const short* __restrict__ aggw,
                                                      const float* __restrict__ aggb,
                                                      float* __restrict__ out) {
    __shared__ short ring[4][8][130][8];               // 66,560 B -> 2 blocks/CU

    const int t   = threadIdx.x;                       // 0..255
    const int lin = blockIdx.x;                        // 0..511
    const int b   = (lin & 7) * 2 + ((lin >> 3) & 1);  // 2 b's per XCD
    const int r0  = (lin >> 4) * 4;                    // 4-row strip

    const int l  = t & 63;
    const int wv = t >> 6;         // 0..3
    const int m  = wv >> 1;        // co half
    const int nh = wv & 1;         // 64-pix window
    const int lm = l & 31;
    const int g  = l >> 5;

    const int sw  = t & 63;        // staging: pix within half
    const int scg = t >> 6;        // staging: 16-ci group

    const float* xb = x + (size_t)b * CI * HH * WW;
    const short* Ab = aggw + (size_t)b * ASTR + (size_t)m * 36 * 512;

    // A-half into registers (36 x bf16x8 = 144 VGPR), coalesced 1KB/wave
    bf16x8 A[36];
#pragma unroll
    for (int ks = 0; ks < 36; ++ks)
        A[ks] = *(const bf16x8*)(Ab + ks * 512 + l * 8);

    float bias[16];
#pragma unroll
    for (int rg = 0; rg < 16; ++rg)
        bias[rg] = aggb[b * CO + m * 32 + (rg & 3) + 8 * (rg >> 2) + 4 * g];

    // zero pix-halo (pix 0 and 129) of all 4 slots
    if (t < 64) {
        int slot = t >> 4, ch = (t >> 1) & 7, px = (t & 1) * 129;
        *(u32x4*)&ring[slot][ch][px][0] = u32x4{0u, 0u, 0u, 0u};
    }

    float pv[16];
    // ---- prologue: rows r0-1, r0, r0+1 -> slots 0,1,2 (two halves each) ----
#pragma unroll
    for (int pr = 0; pr < 3; ++pr) {
        const int r = r0 - 1 + pr;
        const bool rv = ((unsigned)r < 128u);
#pragma unroll
        for (int hf = 0; hf < 2; ++hf) {
            if (rv) load16(xb, r, hf * 64 + sw, scg, pv); else zero16(pv);
            write16(&ring[pr][0][0][0], hf * 64 + sw, scg, pv);
        }
    }
    WAITL0; SBAR;

    // ---- 4 row-steps; each = two 32-pix passes with interleaved staging ----
#pragma unroll
    for (int s = 0; s < 4; ++s) {
        const int r  = r0 + s;
        const int rn = r + 2;                          // row staged this step
        const bool stg = (s < 3);
        const bool rv  = stg && (rn < 128);
        short* wslot = &ring[(s + 3) & 3][0][0][0];

        // ---- pass 0: pix window [nh*64, nh*64+32) ----
        if (stg) { if (rv) load16(xb, rn, 0 * 64 + sw, scg, pv); else zero16(pv); }

        f32x16 acc = (f32x16)0.0f;
#pragma unroll
        for (int ks = 0; ks < 36; ++ks) {
            const int tap = ks >> 2, q = ks & 3;
            const int dy = tap / 3, dx = tap - dy * 3;
            const short* sb = &ring[(s + dy) & 3][0][0][0];
            const int pix = nh * 64 + lm + dx;
            bf16x8 bv = *(const bf16x8*)&sb[((q * 2 + g) * 130 + pix) * 8];
            acc = __builtin_amdgcn_mfma_f32_32x32x16_bf16(A[ks], bv, acc, 0, 0, 0);
        }
        {
            const int wc = nh * 64 + lm;
#pragma unroll
            for (int rg = 0; rg < 16; ++rg) {
                int co = m * 32 + (rg & 3) + 8 * (rg >> 2) + 4 * g;
                out[(((size_t)b * CO + co) * HH + r) * WW + wc] = acc[rg] + bias[rg];
            }
        }
        if (stg) write16(wslot, 0 * 64 + sw, scg, pv); // pv wait covered by pass 0

        // ---- pass 1: pix window [nh*64+32, nh*64+64) ----
        if (stg) { if (rv) load16(xb, rn, 1 * 64 + sw, scg, pv); else zero16(pv); }

        acc = (f32x16)0.0f;
#pragma unroll
        for (int ks = 0; ks < 36; ++ks) {
            const int tap = ks >> 2, q = ks & 3;
            const int dy = tap / 3, dx = tap - dy * 3;
            const short* sb = &ring[(s + dy) & 3][0][0][0];
            const int pix = nh * 64 + 32 + lm + dx;
            bf16x8 bv = *(const bf16x8*)&sb[((q * 2 + g) * 130 + pix) * 8];
            acc = __builtin_amdgcn_mfma_f32_32x32x16_bf16(A[ks], bv, acc, 0, 0, 0);
        }
        {
            const int wc = nh * 64 + 32 + lm;
#pragma unroll
            for (int rg = 0; rg < 16; ++rg) {
                int co = m * 32 + (rg & 3) + 8 * (rg >> 2) + 4 * g;
                out[(((size_t)b * CO + co) * HH + r) * WW + wc] = acc[rg] + bias[rg];
            }
        }
        if (stg) write16(wslot, 1 * 64 + sw, scg, pv); // pv wait covered by pass 1

        WAITL0; SBAR;
    }
}

extern "C" void kernel_launch(void* const* d_in, const int* in_sizes, int n_in,
                              void* d_out, int out_size, void* d_ws, size_t ws_size,
                              hipStream_t stream) {
    const float* x       = (const float*)d_in[0];
    const float* weights = (const float*)d_in[1];
    const float* Wbank   = (const float*)d_in[2];
    const float* bbank   = (const float*)d_in[3];
    float* out = (float*)d_out;

    short* aggw = (short*)d_ws;                          // 1,179,648 B
    float* aggb = (float*)((char*)d_ws + 1179648);       //     4,096 B

    prep_kernel<<<dim3((NB * ASTR) / 256), dim3(256), 0, stream>>>(weights, Wbank, bbank, aggw, aggb);
    conv_kernel<<<dim3(512), dim3(256), 0, stream>>>(x, aggw, aggb, out);
}

// Round 17
// 61.526 us; speedup vs baseline: 1.4225x; 1.4225x over previous
//
#include <hip/hip_runtime.h>
#include <hip/hip_bf16.h>

// Dynamic conv2d: B=16, C_in=64, H=W=128, C_out=64, K=5, ks=3, pad=1.
// R17 = R12 (gll fp32 ring -> LDS convert -> bf16 ring -> MFMA) with 2-row
// steps: shared B-fragments feed dual accumulators (48 ds_read vs 72 per 2
// rows), 2 rows of HBM in flight, FIFO-exact counted vmcnt (glls issued
// before stores -> vmcnt(36)/(32) drain glls only; stores keep ~1.3 steps
// leeway). 5-slot bf16 ring + mid-step mini-barrier frees oldest slot.
// No pv registers (gll staging) -> liveness ~= R12 + 16 AGPR.

typedef __attribute__((ext_vector_type(8))) __bf16 bf16x8;
typedef __attribute__((ext_vector_type(16))) float f32x16;
typedef __attribute__((ext_vector_type(4))) unsigned int u32x4;

#define NB 16
#define CI 64
#define CO 64
#define HH 128
#define WW 128
#define KBANK 5
#define ASTR 36864            // shorts of aggw per b: 2m * 36ks * 2g * 32co5 * 8j

__device__ __forceinline__ unsigned short f2bfu(float f) {
    __hip_bfloat16 h = __float2bfloat16(f);
    unsigned short s;
    __builtin_memcpy(&s, &h, 2);
    return s;
}

// ---------------- kernel 1: aggregate weights + bias ----------------
// aggw per b: [m(2)][ks(36)][g(2)][co5(32)][j(8)]; k = ks*16+g*8+j,
// tap = k>>6, ci = k&63, co = m*32+co5. Wave A-load = contiguous 1KB.
__global__ void prep_kernel(const float* __restrict__ weights,
                            const float* __restrict__ Wbank,
                            const float* __restrict__ bbank,
                            short* __restrict__ aggw,
                            float* __restrict__ aggb) {
    int idx = blockIdx.x * 256 + threadIdx.x;          // < 16*36864
    int b   = idx / ASTR;
    int rem = idx - b * ASTR;
    int j   = rem & 7;
    int co5 = (rem >> 3) & 31;
    int g   = (rem >> 8) & 1;
    int mk  = rem >> 9;
    int m   = mk / 36;
    int ks  = mk - m * 36;
    int co  = m * 32 + co5;
    int k   = ks * 16 + g * 8 + j;
    int tap = k >> 6;
    int ci  = k & 63;
    float s = 0.f;
#pragma unroll
    for (int kk = 0; kk < KBANK; ++kk)
        s += weights[b * KBANK + kk] * Wbank[((kk * CO + co) * CI + ci) * 9 + tap];
    aggw[idx] = (short)f2bfu(s);
    if (k == 0) {
        float sb = 0.f;
#pragma unroll
        for (int kk = 0; kk < KBANK; ++kk)
            sb += weights[b * KBANK + kk] * bbank[kk * CO + co];
        aggb[b * CO + co] = sb;
    }
}

// ---------------- kernel 2: streaming conv, 2-row steps ----------------
#define WAITVN(N) asm volatile("s_waitcnt vmcnt(" #N ")" ::: "memory")
#define WAITL0    asm volatile("s_waitcnt lgkmcnt(0)" ::: "memory")
#define SBAR      do { __builtin_amdgcn_s_barrier(); __builtin_amdgcn_sched_barrier(0); } while (0)

template <int N> struct ic { static constexpr int v = N; };

__global__ __launch_bounds__(512, 2) void conv_kernel(const float* __restrict__ x,
                                                      const short* __restrict__ aggw,
                                                      const float* __restrict__ aggb,
                                                      float* __restrict__ out) {
    __shared__ short bring[5][8][130][8];              // 83,200 B ; slot(row) = (row-(r0-1))%5
    __shared__ float fring[2][64][128];                // 65,536 B ; total 148,736

    const int t   = threadIdx.x;
    const int lin = blockIdx.x;                        // 256 blocks
    const int b   = (lin & 7) * 2 + ((lin >> 3) & 1);  // same-b blocks share an XCD
    const int r0  = (lin >> 4) * 8;                    // 8-row strip

    const int l  = t & 63;
    const int wv = t >> 6;         // 0..7
    const int m  = wv >> 2;        // co half
    const int nq = wv & 3;         // pix quarter
    const int lm = l & 31;
    const int g  = l >> 5;

    const float* xb = x + (size_t)b * CI * HH * WW;
    const short* Ab = aggw + (size_t)b * ASTR + (size_t)m * 36 * 512;

    // A-half in registers (36 x bf16x8), coalesced 1KB/wave loads
    bf16x8 A[36];
#pragma unroll
    for (int ks = 0; ks < 36; ++ks)
        A[ks] = *(const bf16x8*)(Ab + ks * 512 + l * 8);

    float bias[16];
#pragma unroll
    for (int rg = 0; rg < 16; ++rg)
        bias[rg] = aggb[b * CO + m * 32 + (rg & 3) + 8 * (rg >> 2) + 4 * g];

    // zero pix-halo (pix 0 and 129) of all 5 slots
    if (t < 80) {
        int slot = t >> 4, ch = (t >> 1) & 7, px = (t & 1) * 129;
        *(u32x4*)&bring[slot][ch][px][0] = u32x4{0u, 0u, 0u, 0u};
    }

    // stage row r -> fp32 slot fs (4 gll/thread, zero regs); caller clamps r
    auto stage = [&](int r, int fs) {
        float* fbase = &fring[fs][0][0];
#pragma unroll
        for (int i = 0; i < 4; ++i) {
            int c  = i * 512 + t;
            int ci = c >> 5;
            int w  = (c & 31) * 4;
            const float* src = xb + ((size_t)ci * HH + r) * WW + w;
            float* dst = fbase + (size_t)(i * 512 + (t & ~63)) * 4;
            __builtin_amdgcn_global_load_lds(
                (const __attribute__((address_space(1))) void*)src,
                (__attribute__((address_space(3))) void*)dst, 16, 0, 0);
        }
    };
    // convert fring[fs] -> bring slot bs ; zero => write zeros (no fring read)
    auto convz = [&](int fs, int bs, bool zero) {
        const float* fbase = &fring[fs][0][0];
#pragma unroll
        for (int k2 = 0; k2 < 2; ++k2) {
            int c   = k2 * 512 + t;
            int ch  = c >> 7;
            int pix = (c & 127) + 1;
            unsigned u0 = 0, u1 = 0, u2 = 0, u3 = 0;
            if (!zero) {
                const float* p = fbase + ch * 1024 + (pix - 1);
                u0 = (unsigned)f2bfu(p[0])   | ((unsigned)f2bfu(p[128]) << 16);
                u1 = (unsigned)f2bfu(p[256]) | ((unsigned)f2bfu(p[384]) << 16);
                u2 = (unsigned)f2bfu(p[512]) | ((unsigned)f2bfu(p[640]) << 16);
                u3 = (unsigned)f2bfu(p[768]) | ((unsigned)f2bfu(p[896]) << 16);
            }
            *(u32x4*)&bring[bs][ch][pix][0] = u32x4{u0, u1, u2, u3};
        }
    };

    // ---- prologue: rows r0-1..r0+2 -> slots 0..3; glls r0+3->f0, r0+4->f1 ----
    stage(r0 > 0 ? r0 - 1 : 0, 0);
    stage(r0, 1);
    WAITVN(4); SBAR;
    convz(0, 0, r0 == 0);
    WAITVN(0); WAITL0; SBAR;
    convz(1, 1, false);
    stage(r0 + 1, 0);
    WAITL0; SBAR;
    WAITVN(0); SBAR;
    convz(0, 2, false);
    stage(r0 + 2, 1);
    WAITL0; SBAR;
    WAITVN(0); SBAR;
    convz(1, 3, false);
    WAITL0;
    stage(r0 + 3, 0);
    SBAR;                                              // conv f1 done block-wide
    stage(r0 + 4, 1);
    // entering loop: per-wave vmem queue = [gll4(r0+3)][gll4(r0+4)]

    auto stepf = [&](auto Sc) {
        constexpr int s = decltype(Sc)::v;
        const int r = r0 + 2 * s;                      // output rows r, r+1
        const int pixb = nq * 32 + lm;

        if constexpr (s < 3) {
            if constexpr (s == 0) { WAITVN(4); } else { WAITVN(36); }  // gll(r+3) landed
            convz(0, (2 * s + 4) % 5, false);          // row r+3 (always in range)
        }

        f32x16 acc0 = (f32x16)0.0f;
        f32x16 acc1 = (f32x16)0.0f;

        // dy0 cluster: row r-1 (slot (2s)%5) -> acc0 taps 0..2
        {
            const short* sb = &bring[(2 * s) % 5][0][0][0];
#pragma unroll
            for (int dx = 0; dx < 3; ++dx)
#pragma unroll
                for (int q = 0; q < 4; ++q) {
                    bf16x8 bv = *(const bf16x8*)&sb[((q * 2 + g) * 130 + pixb + dx) * 8];
                    acc0 = __builtin_amdgcn_mfma_f32_32x32x16_bf16(A[dx * 4 + q], bv, acc0, 0, 0, 0);
                }
        }

        if constexpr (s < 3) {
            WAITL0; SBAR;                              // barB: row r-1 slot free
            if constexpr (s == 0) { WAITVN(0); } else { WAITVN(32); }  // gll(r+4) landed
            convz(1, (2 * s) % 5, (r0 + 2 * s + 4) > 127);             // row r+4
            if constexpr (s < 2) stage(r + 5, 0);      // r+5 <= r0+7 <= 127
        }

        // rows r (o=1), r+1 (o=2): each fragment read once, feeds both accs
#pragma unroll
        for (int o = 1; o <= 2; ++o) {
            const short* sb = &bring[(2 * s + o) % 5][0][0][0];
#pragma unroll
            for (int dx = 0; dx < 3; ++dx)
#pragma unroll
                for (int q = 0; q < 4; ++q) {
                    bf16x8 bv = *(const bf16x8*)&sb[((q * 2 + g) * 130 + pixb + dx) * 8];
                    acc0 = __builtin_amdgcn_mfma_f32_32x32x16_bf16(A[(o * 3 + dx) * 4 + q], bv, acc0, 0, 0, 0);
                    acc1 = __builtin_amdgcn_mfma_f32_32x32x16_bf16(A[((o - 1) * 3 + dx) * 4 + q], bv, acc1, 0, 0, 0);
                }
        }
        // row r+2 (slot (2s+3)%5): acc1 taps 6..8
        {
            const short* sb = &bring[(2 * s + 3) % 5][0][0][0];
#pragma unroll
            for (int dx = 0; dx < 3; ++dx)
#pragma unroll
                for (int q = 0; q < 4; ++q) {
                    bf16x8 bv = *(const bf16x8*)&sb[((q * 2 + g) * 130 + pixb + dx) * 8];
                    acc1 = __builtin_amdgcn_mfma_f32_32x32x16_bf16(A[(6 + dx) * 4 + q], bv, acc1, 0, 0, 0);
                }
        }

        if constexpr (s < 3) { WAITL0; SBAR; }         // barC: publish slots
        if constexpr (s < 2) {
            int r6 = r + 6; if (r6 > 127) r6 = 127;    // clamp-issue keeps counts uniform
            stage(r6, 1);
        }

        // stores AFTER the glls (FIFO: glls stay oldest-first for next WAITVN)
        const int wc = pixb;
#pragma unroll
        for (int rg = 0; rg < 16; ++rg) {
            int co = m * 32 + (rg & 3) + 8 * (rg >> 2) + 4 * g;
            out[(((size_t)b * CO + co) * HH + r) * WW + wc] = acc0[rg] + bias[rg];
        }
#pragma unroll
        for (int rg = 0; rg < 16; ++rg) {
            int co = m * 32 + (rg & 3) + 8 * (rg >> 2) + 4 * g;
            out[(((size_t)b * CO + co) * HH + (r + 1)) * WW + wc] = acc1[rg] + bias[rg];
        }
    };

    stepf(ic<0>{});
    stepf(ic<1>{});
    stepf(ic<2>{});
    stepf(ic<3>{});
}

extern "C" void kernel_launch(void* const* d_in, const int* in_sizes, int n_in,
                              void* d_out, int out_size, void* d_ws, size_t ws_size,
                              hipStream_t stream) {
    const float* x       = (const float*)d_in[0];
    const float* weights = (const float*)d_in[1];
    const float* Wbank   = (const float*)d_in[2];
    const float* bbank   = (const float*)d_in[3];
    float* out = (float*)d_out;

    short* aggw = (short*)d_ws;                          // 1,179,648 B
    float* aggb = (float*)((char*)d_ws + 1179648);       //     4,096 B

    prep_kernel<<<dim3((NB * ASTR) / 256), dim3(256), 0, stream>>>(weights, Wbank, bbank, aggw, aggb);
    conv_kernel<<<dim3(256), dim3(512), 0, stream>>>(x, aggw, aggb, out);
}

// Round 18
// 46.270 us; speedup vs baseline: 1.8916x; 1.3297x over previous
//
#include <hip/hip_runtime.h>
#include <hip/hip_bf16.h>

// Dynamic conv2d: B=16, C_in=64, H=W=128, C_out=64, K=5, ks=3, pad=1.
// R18 = R12 (champion: gll fp32 ring -> LDS convert -> bf16 ring -> MFMA,
// split-barrier publish) + liveness-neutral micro-edits only:
//   1. gll stage(r+3) issued BEFORE convert (more latency cover; FIFO counts
//      unchanged: stores still issued after glls each step).
//   2. s_setprio(1) around the MFMA cluster (T5).
// Everything else byte-identical to R12.

typedef __attribute__((ext_vector_type(8))) __bf16 bf16x8;
typedef __attribute__((ext_vector_type(16))) float f32x16;
typedef __attribute__((ext_vector_type(4))) unsigned int u32x4;

#define NB 16
#define CI 64
#define CO 64
#define HH 128
#define WW 128
#define KBANK 5
#define ASTR 36864            // shorts of aggw per b: 2m * 36ks * 2g * 32co5 * 8j

__device__ __forceinline__ unsigned short f2bfu(float f) {
    __hip_bfloat16 h = __float2bfloat16(f);
    unsigned short s;
    __builtin_memcpy(&s, &h, 2);
    return s;
}

// ---------------- kernel 1: aggregate weights + bias ----------------
// aggw per b: [m(2)][ks(36)][g(2)][co5(32)][j(8)]; k = ks*16+g*8+j,
// tap = k>>6, ci = k&63, co = m*32+co5. Wave A-load = contiguous 1KB.
__global__ void prep_kernel(const float* __restrict__ weights,
                            const float* __restrict__ Wbank,
                            const float* __restrict__ bbank,
                            short* __restrict__ aggw,
                            float* __restrict__ aggb) {
    int idx = blockIdx.x * 256 + threadIdx.x;          // < 16*36864
    int b   = idx / ASTR;
    int rem = idx - b * ASTR;
    int j   = rem & 7;
    int co5 = (rem >> 3) & 31;
    int g   = (rem >> 8) & 1;
    int mk  = rem >> 9;
    int m   = mk / 36;
    int ks  = mk - m * 36;
    int co  = m * 32 + co5;
    int k   = ks * 16 + g * 8 + j;
    int tap = k >> 6;
    int ci  = k & 63;
    float s = 0.f;
#pragma unroll
    for (int kk = 0; kk < KBANK; ++kk)
        s += weights[b * KBANK + kk] * Wbank[((kk * CO + co) * CI + ci) * 9 + tap];
    aggw[idx] = (short)f2bfu(s);
    if (k == 0) {
        float sb = 0.f;
#pragma unroll
        for (int kk = 0; kk < KBANK; ++kk)
            sb += weights[b * KBANK + kk] * bbank[kk * CO + co];
        aggb[b * CO + co] = sb;
    }
}

// ---------------- kernel 2: streaming conv ----------------
#define WAITV(N) asm volatile("s_waitcnt vmcnt(" #N ")" ::: "memory")
#define WAITL0   asm volatile("s_waitcnt lgkmcnt(0)" ::: "memory")
#define SBAR     do { __builtin_amdgcn_s_barrier(); __builtin_amdgcn_sched_barrier(0); } while (0)

__global__ __launch_bounds__(512, 2) void conv_kernel(const float* __restrict__ x,
                                                      const short* __restrict__ aggw,
                                                      const float* __restrict__ aggb,
                                                      float* __restrict__ out) {
    __shared__ short bring[4][8][130][8];              // bf16 ring, 66,560 B
    __shared__ float fring[2][64][128];                // fp32 ring, 65,536 B

    const int t   = threadIdx.x;
    const int lin = blockIdx.x;                        // 256 blocks
    const int b   = (lin & 7) * 2 + ((lin >> 3) & 1);  // same-b blocks share an XCD
    const int r0  = (lin >> 4) * 8;                    // 8-row strip

    const int l  = t & 63;
    const int wv = t >> 6;         // 0..7
    const int m  = wv >> 2;        // co half
    const int nq = wv & 3;         // pix quarter
    const int lm = l & 31;
    const int g  = l >> 5;

    const float* xb = x + (size_t)b * CI * HH * WW;
    const short* Ab = aggw + (size_t)b * ASTR + (size_t)m * 36 * 512;

    // A-half into registers (36 x bf16x8), coalesced 1KB/wave loads
    bf16x8 A[36];
#pragma unroll
    for (int ks = 0; ks < 36; ++ks)
        A[ks] = *(const bf16x8*)(Ab + ks * 512 + l * 8);

    float bias[16];
#pragma unroll
    for (int rg = 0; rg < 16; ++rg)
        bias[rg] = aggb[b * CO + m * 32 + (rg & 3) + 8 * (rg >> 2) + 4 * g];

    // zero pix-halo (pix 0 and 129) of all 4 bf16 slots
    if (t < 64) {
        int slot = t >> 4, ch = (t >> 1) & 7, px = (t & 1) * 129;
        *(u32x4*)&bring[slot][ch][px][0] = u32x4{0u, 0u, 0u, 0u};
    }

    // stage: row r -> fp32 slot fs via global_load_lds (4 chunks/thread, 0 regs)
    auto stage = [&](int r, int fs) {
        float* fbase = &fring[fs][0][0];
#pragma unroll
        for (int i = 0; i < 4; ++i) {
            int c  = i * 512 + t;                      // chunk id, 16B each
            int ci = c >> 5;
            int w  = (c & 31) * 4;
            const float* src = xb + ((size_t)ci * HH + r) * WW + w;
            float* dst = fbase + (size_t)(i * 512 + (t & ~63)) * 4;  // wave-uniform base
            __builtin_amdgcn_global_load_lds(
                (const __attribute__((address_space(1))) void*)src,
                (__attribute__((address_space(3))) void*)dst, 16, 0, 0);
        }
    };

    // convert: fp32 slot -> bf16 ring slot bs (2 chunks/thread); zero => write 0s
    auto convertz = [&](const float* fbase, int bs, bool zero) {
#pragma unroll
        for (int k2 = 0; k2 < 2; ++k2) {
            int c   = k2 * 512 + t;
            int ch  = c >> 7;
            int pix = (c & 127) + 1;
            unsigned u0 = 0, u1 = 0, u2 = 0, u3 = 0;
            if (!zero) {
                const float* p = fbase + ch * 1024 + (pix - 1);
                u0 = (unsigned)f2bfu(p[0])   | ((unsigned)f2bfu(p[128]) << 16);
                u1 = (unsigned)f2bfu(p[256]) | ((unsigned)f2bfu(p[384]) << 16);
                u2 = (unsigned)f2bfu(p[512]) | ((unsigned)f2bfu(p[640]) << 16);
                u3 = (unsigned)f2bfu(p[768]) | ((unsigned)f2bfu(p[896]) << 16);
            }
            *(u32x4*)&bring[bs][ch][pix][0] = u32x4{u0, u1, u2, u3};
        }
    };

    // ---- prologue: bring rows r0-1,r0,r0+1 -> slots 0,1,2 ; gll(r0+2)->f0 left in flight
    if (r0 > 0) stage(r0 - 1, 1);                      // f1
    stage(r0, 0);                                      // f0
    WAITV(4); SBAR;                                    // r0-1 landed everywhere
    if (r0 > 0) convertz(&fring[1][0][0], 0, false);
    else        convertz(nullptr,         0, true);
    WAITV(0);                                          // r0 landed (own)
    WAITL0; SBAR;                                      // publish bring0 + r0 landing
    convertz(&fring[0][0][0], 1, false);               // r0 -> bring1
    stage(r0 + 1, 1);                                  // f1 (its reads drained above)
    WAITL0; SBAR;                                      // publish bring1
    WAITV(0); SBAR;                                    // r0+1 landed everywhere
    convertz(&fring[1][0][0], 2, false);               // r0+1 -> bring2
    stage(r0 + 2, 0);                                  // f0 (reads drained 2 barriers ago)
    WAITL0; SBAR;                                      // publish bring2; gll(r0+2) in flight

    // ---- 8 row-steps, split-barrier publish ----
#pragma unroll
    for (int s = 0; s < 8; ++s) {
        const int r = r0 + s;

        // drain own gll issued LAST step (full step of cover), then publish
        if (s == 0) { WAITV(0); } else { WAITV(16); }
        SBAR;

        // issue next row's gll FIRST (max cover; still older than this step's stores)
        if (s <= 5 && r + 3 <= 127) stage(r + 3, (s + 1) & 1);

        // convert row r+2 (fring slot s&1) -> bring slot (s+3)&3 ; only if used
        if (s <= 6) {
            if (r + 2 <= 127) convertz(&fring[s & 1][0][0], (s + 3) & 3, false);
            else              convertz(nullptr,             (s + 3) & 3, true);
        }

        // MFMA: output row r from bf16 slots (s, s+1, s+2)
        f32x16 acc = (f32x16)0.0f;
        __builtin_amdgcn_s_setprio(1);
#pragma unroll
        for (int ks = 0; ks < 36; ++ks) {
            const int tap = ks >> 2, q = ks & 3;
            const int dy = tap / 3, dx = tap - dy * 3;
            const short* sb = &bring[(s + dy) & 3][0][0][0];
            const int pix = nq * 32 + dx + lm;
            bf16x8 bv = *(const bf16x8*)&sb[((q * 2 + g) * 130 + pix) * 8];
            acc = __builtin_amdgcn_mfma_f32_32x32x16_bf16(A[ks], bv, acc, 0, 0, 0);
        }
        __builtin_amdgcn_s_setprio(0);

        // output stores (fire-and-forget; retired by NEXT step's WAITV(16))
        const int wc = nq * 32 + lm;
#pragma unroll
        for (int rg = 0; rg < 16; ++rg) {
            int co = m * 32 + (rg & 3) + 8 * (rg >> 2) + 4 * g;
            out[(((size_t)b * CO + co) * HH + r) * WW + wc] = acc[rg] + bias[rg];
        }

        // end-of-step: drain LDS ops only (stores + gll stay in flight)
        WAITL0;
        SBAR;
    }
}

extern "C" void kernel_launch(void* const* d_in, const int* in_sizes, int n_in,
                              void* d_out, int out_size, void* d_ws, size_t ws_size,
                              hipStream_t stream) {
    const float* x       = (const float*)d_in[0];
    const float* weights = (const float*)d_in[1];
    const float* Wbank   = (const float*)d_in[2];
    const float* bbank   = (const float*)d_in[3];
    float* out = (float*)d_out;

    short* aggw = (short*)d_ws;                          // 1,179,648 B
    float* aggb = (float*)((char*)d_ws + 1179648);       //     4,096 B

    prep_kernel<<<dim3((NB * ASTR) / 256), dim3(256), 0, stream>>>(weights, Wbank, bbank, aggw, aggb);
    conv_kernel<<<dim3(256), dim3(512), 0, stream>>>(x, aggw, aggb, out);
}

// Round 19
// 39.876 us; speedup vs baseline: 2.1949x; 1.1604x over previous
//
#include <hip/hip_runtime.h>
#include <hip/hip_bf16.h>

// Dynamic conv2d: B=16, C_in=64, H=W=128, C_out=64, K=5, ks=3, pad=1.
// R19 = exact restore of R12 (session champion, 40.05 us total):
// gll-staged fp32 ring -> LDS convert -> bf16 ring -> MFMA 32x32x16,
// split-barrier publish (own-gll drain at next-step START), counted
// vmcnt(16) keeps stores + next-row loads in flight, A[36] in registers.
// Every deviation tried (R13-R18) regressed via spill or latency chains.

typedef __attribute__((ext_vector_type(8))) __bf16 bf16x8;
typedef __attribute__((ext_vector_type(16))) float f32x16;
typedef __attribute__((ext_vector_type(4))) unsigned int u32x4;

#define NB 16
#define CI 64
#define CO 64
#define HH 128
#define WW 128
#define KBANK 5
#define ASTR 36864            // shorts of aggw per b: 2m * 36ks * 2g * 32co5 * 8j

__device__ __forceinline__ unsigned short f2bfu(float f) {
    __hip_bfloat16 h = __float2bfloat16(f);
    unsigned short s;
    __builtin_memcpy(&s, &h, 2);
    return s;
}

// ---------------- kernel 1: aggregate weights + bias ----------------
// aggw per b: [m(2)][ks(36)][g(2)][co5(32)][j(8)]; k = ks*16+g*8+j,
// tap = k>>6, ci = k&63, co = m*32+co5. Wave A-load = contiguous 1KB.
__global__ void prep_kernel(const float* __restrict__ weights,
                            const float* __restrict__ Wbank,
                            const float* __restrict__ bbank,
                            short* __restrict__ aggw,
                            float* __restrict__ aggb) {
    int idx = blockIdx.x * 256 + threadIdx.x;          // < 16*36864
    int b   = idx / ASTR;
    int rem = idx - b * ASTR;
    int j   = rem & 7;
    int co5 = (rem >> 3) & 31;
    int g   = (rem >> 8) & 1;
    int mk  = rem >> 9;
    int m   = mk / 36;
    int ks  = mk - m * 36;
    int co  = m * 32 + co5;
    int k   = ks * 16 + g * 8 + j;
    int tap = k >> 6;
    int ci  = k & 63;
    float s = 0.f;
#pragma unroll
    for (int kk = 0; kk < KBANK; ++kk)
        s += weights[b * KBANK + kk] * Wbank[((kk * CO + co) * CI + ci) * 9 + tap];
    aggw[idx] = (short)f2bfu(s);
    if (k == 0) {
        float sb = 0.f;
#pragma unroll
        for (int kk = 0; kk < KBANK; ++kk)
            sb += weights[b * KBANK + kk] * bbank[kk * CO + co];
        aggb[b * CO + co] = sb;
    }
}

// ---------------- kernel 2: streaming conv ----------------
#define WAITV(N) asm volatile("s_waitcnt vmcnt(" #N ")" ::: "memory")
#define WAITL0   asm volatile("s_waitcnt lgkmcnt(0)" ::: "memory")
#define SBAR     do { __builtin_amdgcn_s_barrier(); __builtin_amdgcn_sched_barrier(0); } while (0)

__global__ __launch_bounds__(512, 2) void conv_kernel(const float* __restrict__ x,
                                                      const short* __restrict__ aggw,
                                                      const float* __restrict__ aggb,
                                                      float* __restrict__ out) {
    __shared__ short bring[4][8][130][8];              // bf16 ring, 66,560 B
    __shared__ float fring[2][64][128];                // fp32 ring, 65,536 B

    const int t   = threadIdx.x;
    const int lin = blockIdx.x;                        // 256 blocks
    const int b   = (lin & 7) * 2 + ((lin >> 3) & 1);  // same-b blocks share an XCD
    const int r0  = (lin >> 4) * 8;                    // 8-row strip

    const int l  = t & 63;
    const int wv = t >> 6;         // 0..7
    const int m  = wv >> 2;        // co half
    const int nq = wv & 3;         // pix quarter
    const int lm = l & 31;
    const int g  = l >> 5;

    const float* xb = x + (size_t)b * CI * HH * WW;
    const short* Ab = aggw + (size_t)b * ASTR + (size_t)m * 36 * 512;

    // A-half into registers (36 x bf16x8), coalesced 1KB/wave loads
    bf16x8 A[36];
#pragma unroll
    for (int ks = 0; ks < 36; ++ks)
        A[ks] = *(const bf16x8*)(Ab + ks * 512 + l * 8);

    float bias[16];
#pragma unroll
    for (int rg = 0; rg < 16; ++rg)
        bias[rg] = aggb[b * CO + m * 32 + (rg & 3) + 8 * (rg >> 2) + 4 * g];

    // zero pix-halo (pix 0 and 129) of all 4 bf16 slots
    if (t < 64) {
        int slot = t >> 4, ch = (t >> 1) & 7, px = (t & 1) * 129;
        *(u32x4*)&bring[slot][ch][px][0] = u32x4{0u, 0u, 0u, 0u};
    }

    // stage: row r -> fp32 slot fs via global_load_lds (4 chunks/thread, 0 regs)
    auto stage = [&](int r, int fs) {
        float* fbase = &fring[fs][0][0];
#pragma unroll
        for (int i = 0; i < 4; ++i) {
            int c  = i * 512 + t;                      // chunk id, 16B each
            int ci = c >> 5;
            int w  = (c & 31) * 4;
            const float* src = xb + ((size_t)ci * HH + r) * WW + w;
            float* dst = fbase + (size_t)(i * 512 + (t & ~63)) * 4;  // wave-uniform base
            __builtin_amdgcn_global_load_lds(
                (const __attribute__((address_space(1))) void*)src,
                (__attribute__((address_space(3))) void*)dst, 16, 0, 0);
        }
    };

    // convert: fp32 slot -> bf16 ring slot bs (2 chunks/thread); zero => write 0s
    auto convertz = [&](const float* fbase, int bs, bool zero) {
#pragma unroll
        for (int k2 = 0; k2 < 2; ++k2) {
            int c   = k2 * 512 + t;
            int ch  = c >> 7;
            int pix = (c & 127) + 1;
            unsigned u0 = 0, u1 = 0, u2 = 0, u3 = 0;
            if (!zero) {
                const float* p = fbase + ch * 1024 + (pix - 1);
                u0 = (unsigned)f2bfu(p[0])   | ((unsigned)f2bfu(p[128]) << 16);
                u1 = (unsigned)f2bfu(p[256]) | ((unsigned)f2bfu(p[384]) << 16);
                u2 = (unsigned)f2bfu(p[512]) | ((unsigned)f2bfu(p[640]) << 16);
                u3 = (unsigned)f2bfu(p[768]) | ((unsigned)f2bfu(p[896]) << 16);
            }
            *(u32x4*)&bring[bs][ch][pix][0] = u32x4{u0, u1, u2, u3};
        }
    };

    // ---- prologue: bring rows r0-1,r0,r0+1 -> slots 0,1,2 ; gll(r0+2)->f0 left in flight
    if (r0 > 0) stage(r0 - 1, 1);                      // f1
    stage(r0, 0);                                      // f0
    WAITV(4); SBAR;                                    // r0-1 landed everywhere
    if (r0 > 0) convertz(&fring[1][0][0], 0, false);
    else        convertz(nullptr,         0, true);
    WAITV(0);                                          // r0 landed (own)
    WAITL0; SBAR;                                      // publish bring0 + r0 landing
    convertz(&fring[0][0][0], 1, false);               // r0 -> bring1
    stage(r0 + 1, 1);                                  // f1 (its reads drained above)
    WAITL0; SBAR;                                      // publish bring1
    WAITV(0); SBAR;                                    // r0+1 landed everywhere
    convertz(&fring[1][0][0], 2, false);               // r0+1 -> bring2
    stage(r0 + 2, 0);                                  // f0 (reads drained 2 barriers ago)
    WAITL0; SBAR;                                      // publish bring2; gll(r0+2) in flight

    // ---- 8 row-steps, split-barrier publish ----
#pragma unroll
    for (int s = 0; s < 8; ++s) {
        const int r = r0 + s;

        // drain own gll issued LAST step (full step of cover), then publish
        if (s == 0) { WAITV(0); } else { WAITV(16); }
        SBAR;

        // convert row r+2 (fring slot s&1) -> bring slot (s+3)&3 ; only if used
        if (s <= 6) {
            if (r + 2 <= 127) convertz(&fring[s & 1][0][0], (s + 3) & 3, false);
            else              convertz(nullptr,             (s + 3) & 3, true);
        }

        // issue next row's gll (drained at start of next step)
        if (s <= 5 && r + 3 <= 127) stage(r + 3, (s + 1) & 1);

        // MFMA: output row r from bf16 slots (s, s+1, s+2)
        f32x16 acc = (f32x16)0.0f;
#pragma unroll
        for (int ks = 0; ks < 36; ++ks) {
            const int tap = ks >> 2, q = ks & 3;
            const int dy = tap / 3, dx = tap - dy * 3;
            const short* sb = &bring[(s + dy) & 3][0][0][0];
            const int pix = nq * 32 + dx + lm;
            bf16x8 bv = *(const bf16x8*)&sb[((q * 2 + g) * 130 + pix) * 8];
            acc = __builtin_amdgcn_mfma_f32_32x32x16_bf16(A[ks], bv, acc, 0, 0, 0);
        }

        // output stores (fire-and-forget; retired by NEXT step's WAITV(16))
        const int wc = nq * 32 + lm;
#pragma unroll
        for (int rg = 0; rg < 16; ++rg) {
            int co = m * 32 + (rg & 3) + 8 * (rg >> 2) + 4 * g;
            out[(((size_t)b * CO + co) * HH + r) * WW + wc] = acc[rg] + bias[rg];
        }

        // end-of-step: drain LDS ops only (stores + gll stay in flight)
        WAITL0;
        SBAR;
    }
}

extern "C" void kernel_launch(void* const* d_in, const int* in_sizes, int n_in,
                              void* d_out, int out_size, void* d_ws, size_t ws_size,
                              hipStream_t stream) {
    const float* x       = (const float*)d_in[0];
    const float* weights = (const float*)d_in[1];
    const float* Wbank   = (const float*)d_in[2];
    const float* bbank   = (const float*)d_in[3];
    float* out = (float*)d_out;

    short* aggw = (short*)d_ws;                          // 1,179,648 B
    float* aggb = (float*)((char*)d_ws + 1179648);       //     4,096 B

    prep_kernel<<<dim3((NB * ASTR) / 256), dim3(256), 0, stream>>>(weights, Wbank, bbank, aggw, aggb);
    conv_kernel<<<dim3(256), dim3(512), 0, stream>>>(x, aggw, aggb, out);
}

// Round 21
// 39.874 us; speedup vs baseline: 2.1950x; 1.0000x over previous
//
#include <hip/hip_runtime.h>
#include <hip/hip_bf16.h>

// Dynamic conv2d: B=16, C_in=64, H=W=128, C_out=64, K=5, ks=3, pad=1.
// FINAL = exact restore of R12/R19 (session champion, 39.88 us total):
// gll-staged fp32 ring -> LDS convert -> bf16 ring -> MFMA 32x32x16,
// split-barrier publish (own-gll drain at next-step START), counted
// vmcnt(16) keeps stores + next-row loads in flight, A[36] in registers.
// All structural deviations tried (R13-R18, R20) regressed via spill,
// latency chains, starvation, or races. The register file (A=144 VGPR +
// one f32x16 acc) is the binding constraint of this op on gfx950.

typedef __attribute__((ext_vector_type(8))) __bf16 bf16x8;
typedef __attribute__((ext_vector_type(16))) float f32x16;
typedef __attribute__((ext_vector_type(4))) unsigned int u32x4;

#define NB 16
#define CI 64
#define CO 64
#define HH 128
#define WW 128
#define KBANK 5
#define ASTR 36864            // shorts of aggw per b: 2m * 36ks * 2g * 32co5 * 8j

__device__ __forceinline__ unsigned short f2bfu(float f) {
    __hip_bfloat16 h = __float2bfloat16(f);
    unsigned short s;
    __builtin_memcpy(&s, &h, 2);
    return s;
}

// ---------------- kernel 1: aggregate weights + bias ----------------
// aggw per b: [m(2)][ks(36)][g(2)][co5(32)][j(8)]; k = ks*16+g*8+j,
// tap = k>>6, ci = k&63, co = m*32+co5. Wave A-load = contiguous 1KB.
__global__ void prep_kernel(const float* __restrict__ weights,
                            const float* __restrict__ Wbank,
                            const float* __restrict__ bbank,
                            short* __restrict__ aggw,
                            float* __restrict__ aggb) {
    int idx = blockIdx.x * 256 + threadIdx.x;          // < 16*36864
    int b   = idx / ASTR;
    int rem = idx - b * ASTR;
    int j   = rem & 7;
    int co5 = (rem >> 3) & 31;
    int g   = (rem >> 8) & 1;
    int mk  = rem >> 9;
    int m   = mk / 36;
    int ks  = mk - m * 36;
    int co  = m * 32 + co5;
    int k   = ks * 16 + g * 8 + j;
    int tap = k >> 6;
    int ci  = k & 63;
    float s = 0.f;
#pragma unroll
    for (int kk = 0; kk < KBANK; ++kk)
        s += weights[b * KBANK + kk] * Wbank[((kk * CO + co) * CI + ci) * 9 + tap];
    aggw[idx] = (short)f2bfu(s);
    if (k == 0) {
        float sb = 0.f;
#pragma unroll
        for (int kk = 0; kk < KBANK; ++kk)
            sb += weights[b * KBANK + kk] * bbank[kk * CO + co];
        aggb[b * CO + co] = sb;
    }
}

// ---------------- kernel 2: streaming conv ----------------
#define WAITV(N) asm volatile("s_waitcnt vmcnt(" #N ")" ::: "memory")
#define WAITL0   asm volatile("s_waitcnt lgkmcnt(0)" ::: "memory")
#define SBAR     do { __builtin_amdgcn_s_barrier(); __builtin_amdgcn_sched_barrier(0); } while (0)

__global__ __launch_bounds__(512, 2) void conv_kernel(const float* __restrict__ x,
                                                      const short* __restrict__ aggw,
                                                      const float* __restrict__ aggb,
                                                      float* __restrict__ out) {
    __shared__ short bring[4][8][130][8];              // bf16 ring, 66,560 B
    __shared__ float fring[2][64][128];                // fp32 ring, 65,536 B

    const int t   = threadIdx.x;
    const int lin = blockIdx.x;                        // 256 blocks
    const int b   = (lin & 7) * 2 + ((lin >> 3) & 1);  // same-b blocks share an XCD
    const int r0  = (lin >> 4) * 8;                    // 8-row strip

    const int l  = t & 63;
    const int wv = t >> 6;         // 0..7
    const int m  = wv >> 2;        // co half
    const int nq = wv & 3;         // pix quarter
    const int lm = l & 31;
    const int g  = l >> 5;

    const float* xb = x + (size_t)b * CI * HH * WW;
    const short* Ab = aggw + (size_t)b * ASTR + (size_t)m * 36 * 512;

    // A-half into registers (36 x bf16x8), coalesced 1KB/wave loads
    bf16x8 A[36];
#pragma unroll
    for (int ks = 0; ks < 36; ++ks)
        A[ks] = *(const bf16x8*)(Ab + ks * 512 + l * 8);

    float bias[16];
#pragma unroll
    for (int rg = 0; rg < 16; ++rg)
        bias[rg] = aggb[b * CO + m * 32 + (rg & 3) + 8 * (rg >> 2) + 4 * g];

    // zero pix-halo (pix 0 and 129) of all 4 bf16 slots
    if (t < 64) {
        int slot = t >> 4, ch = (t >> 1) & 7, px = (t & 1) * 129;
        *(u32x4*)&bring[slot][ch][px][0] = u32x4{0u, 0u, 0u, 0u};
    }

    // stage: row r -> fp32 slot fs via global_load_lds (4 chunks/thread, 0 regs)
    auto stage = [&](int r, int fs) {
        float* fbase = &fring[fs][0][0];
#pragma unroll
        for (int i = 0; i < 4; ++i) {
            int c  = i * 512 + t;                      // chunk id, 16B each
            int ci = c >> 5;
            int w  = (c & 31) * 4;
            const float* src = xb + ((size_t)ci * HH + r) * WW + w;
            float* dst = fbase + (size_t)(i * 512 + (t & ~63)) * 4;  // wave-uniform base
            __builtin_amdgcn_global_load_lds(
                (const __attribute__((address_space(1))) void*)src,
                (__attribute__((address_space(3))) void*)dst, 16, 0, 0);
        }
    };

    // convert: fp32 slot -> bf16 ring slot bs (2 chunks/thread); zero => write 0s
    auto convertz = [&](const float* fbase, int bs, bool zero) {
#pragma unroll
        for (int k2 = 0; k2 < 2; ++k2) {
            int c   = k2 * 512 + t;
            int ch  = c >> 7;
            int pix = (c & 127) + 1;
            unsigned u0 = 0, u1 = 0, u2 = 0, u3 = 0;
            if (!zero) {
                const float* p = fbase + ch * 1024 + (pix - 1);
                u0 = (unsigned)f2bfu(p[0])   | ((unsigned)f2bfu(p[128]) << 16);
                u1 = (unsigned)f2bfu(p[256]) | ((unsigned)f2bfu(p[384]) << 16);
                u2 = (unsigned)f2bfu(p[512]) | ((unsigned)f2bfu(p[640]) << 16);
                u3 = (unsigned)f2bfu(p[768]) | ((unsigned)f2bfu(p[896]) << 16);
            }
            *(u32x4*)&bring[bs][ch][pix][0] = u32x4{u0, u1, u2, u3};
        }
    };

    // ---- prologue: bring rows r0-1,r0,r0+1 -> slots 0,1,2 ; gll(r0+2)->f0 left in flight
    if (r0 > 0) stage(r0 - 1, 1);                      // f1
    stage(r0, 0);                                      // f0
    WAITV(4); SBAR;                                    // r0-1 landed everywhere
    if (r0 > 0) convertz(&fring[1][0][0], 0, false);
    else        convertz(nullptr,         0, true);
    WAITV(0);                                          // r0 landed (own)
    WAITL0; SBAR;                                      // publish bring0 + r0 landing
    convertz(&fring[0][0][0], 1, false);               // r0 -> bring1
    stage(r0 + 1, 1);                                  // f1 (its reads drained above)
    WAITL0; SBAR;                                      // publish bring1
    WAITV(0); SBAR;                                    // r0+1 landed everywhere
    convertz(&fring[1][0][0], 2, false);               // r0+1 -> bring2
    stage(r0 + 2, 0);                                  // f0 (reads drained 2 barriers ago)
    WAITL0; SBAR;                                      // publish bring2; gll(r0+2) in flight

    // ---- 8 row-steps, split-barrier publish ----
#pragma unroll
    for (int s = 0; s < 8; ++s) {
        const int r = r0 + s;

        // drain own gll issued LAST step (full step of cover), then publish
        if (s == 0) { WAITV(0); } else { WAITV(16); }
        SBAR;

        // convert row r+2 (fring slot s&1) -> bring slot (s+3)&3 ; only if used
        if (s <= 6) {
            if (r + 2 <= 127) convertz(&fring[s & 1][0][0], (s + 3) & 3, false);
            else              convertz(nullptr,             (s + 3) & 3, true);
        }

        // issue next row's gll (drained at start of next step)
        if (s <= 5 && r + 3 <= 127) stage(r + 3, (s + 1) & 1);

        // MFMA: output row r from bf16 slots (s, s+1, s+2)
        f32x16 acc = (f32x16)0.0f;
#pragma unroll
        for (int ks = 0; ks < 36; ++ks) {
            const int tap = ks >> 2, q = ks & 3;
            const int dy = tap / 3, dx = tap - dy * 3;
            const short* sb = &bring[(s + dy) & 3][0][0][0];
            const int pix = nq * 32 + dx + lm;
            bf16x8 bv = *(const bf16x8*)&sb[((q * 2 + g) * 130 + pix) * 8];
            acc = __builtin_amdgcn_mfma_f32_32x32x16_bf16(A[ks], bv, acc, 0, 0, 0);
        }

        // output stores (fire-and-forget; retired by NEXT step's WAITV(16))
        const int wc = nq * 32 + lm;
#pragma unroll
        for (int rg = 0; rg < 16; ++rg) {
            int co = m * 32 + (rg & 3) + 8 * (rg >> 2) + 4 * g;
            out[(((size_t)b * CO + co) * HH + r) * WW + wc] = acc[rg] + bias[rg];
        }

        // end-of-step: drain LDS ops only (stores + gll stay in flight)
        WAITL0;
        SBAR;
    }
}

extern "C" void kernel_launch(void* const* d_in, const int* in_sizes, int n_in,
                              void* d_out, int out_size, void* d_ws, size_t ws_size,
                              hipStream_t stream) {
    const float* x       = (const float*)d_in[0];
    const float* weights = (const float*)d_in[1];
    const float* Wbank   = (const float*)d_in[2];
    const float* bbank   = (const float*)d_in[3];
    float* out = (float*)d_out;

    short* aggw = (short*)d_ws;                          // 1,179,648 B
    float* aggb = (float*)((char*)d_ws + 1179648);       //     4,096 B

    prep_kernel<<<dim3((NB * ASTR) / 256), dim3(256), 0, stream>>>(weights, Wbank, bbank, aggw, aggb);
    conv_kernel<<<dim3(256), dim3(512), 0, stream>>>(x, aggw, aggb, out);
}